// Round 5
// baseline (200.693 us; speedup 1.0000x reference)
//
#include <hip/hip_runtime.h>

// out[r] = sum_{s in ray r} w[s] * rgb[s,:]  (segment_ids sorted, fp32)
// Persistent waves, register double-buffered grid-stride loop:
//   - each wave processes chunks of 256 contiguous samples (4/lane, dwordx4)
//   - next chunk's 5 vector loads issued BEFORE processing current (prefetch)
//   - per-lane run compression + ballot-based segmented shuffle scan
//   - one global atomicAdd triplet per run-end (out pre-zeroed)

#define NTHREADS 256
#define WPB      (NTHREADS / 64)   // waves per block
#define NBLOCKS  1024              // 4096 persistent waves

__global__ __launch_bounds__(NTHREADS) void zero_out_kernel(float4* __restrict__ out4,
                                                            int n4) {
  int i = blockIdx.x * blockDim.x + threadIdx.x;
  if (i < n4) out4[i] = make_float4(0.f, 0.f, 0.f, 0.f);
}

struct Chunk {
  int4 id4;
  float4 w4, r0, r1, r2;
};

__device__ __forceinline__ Chunk load_chunk(const int* __restrict__ ids,
                                            const float* __restrict__ rgb,
                                            const float* __restrict__ w,
                                            long long t0, int n_samples) {
  Chunk c;
  if (t0 + 3 < n_samples) {  // aligned fast path (t0 % 4 == 0)
    c.id4 = *(const int4*)(ids + t0);
    c.w4  = *(const float4*)(w + t0);
    c.r0  = *(const float4*)(rgb + 3 * t0);
    c.r1  = *(const float4*)(rgb + 3 * t0 + 4);
    c.r2  = *(const float4*)(rgb + 3 * t0 + 8);
  } else {  // padded tail (pads: last id, zero weight -> zero contribution)
    int lastid = ids[n_samples - 1];
    int   it[4];
    float wt[4], rt[12];
    #pragma unroll
    for (int j = 0; j < 4; ++j) {
      long long s = t0 + j;
      if (s < n_samples) {
        it[j] = ids[s];
        wt[j] = w[s];
        rt[3 * j + 0] = rgb[3 * s + 0];
        rt[3 * j + 1] = rgb[3 * s + 1];
        rt[3 * j + 2] = rgb[3 * s + 2];
      } else {
        it[j] = lastid;
        wt[j] = 0.f;
        rt[3 * j + 0] = rt[3 * j + 1] = rt[3 * j + 2] = 0.f;
      }
    }
    c.id4 = make_int4(it[0], it[1], it[2], it[3]);
    c.w4  = make_float4(wt[0], wt[1], wt[2], wt[3]);
    c.r0  = make_float4(rt[0], rt[1], rt[2], rt[3]);
    c.r1  = make_float4(rt[4], rt[5], rt[6], rt[7]);
    c.r2  = make_float4(rt[8], rt[9], rt[10], rt[11]);
  }
  return c;
}

__device__ __forceinline__ void process_chunk(const Chunk& c,
                                              float* __restrict__ out,
                                              int lane) {
  const int idv[4] = {c.id4.x, c.id4.y, c.id4.z, c.id4.w};
  float px[4], py[4], pz[4];
  px[0] = c.r0.x * c.w4.x; py[0] = c.r0.y * c.w4.x; pz[0] = c.r0.z * c.w4.x;
  px[1] = c.r0.w * c.w4.y; py[1] = c.r1.x * c.w4.y; pz[1] = c.r1.y * c.w4.y;
  px[2] = c.r1.z * c.w4.z; py[2] = c.r1.w * c.w4.z; pz[2] = c.r2.x * c.w4.z;
  px[3] = c.r2.y * c.w4.w; py[3] = c.r2.z * c.w4.w; pz[3] = c.r2.w * c.w4.w;

  // per-lane run compression (sorted ids: id0==id3 => all four equal)
  const int id0 = idv[0], id3 = idv[3];
  const bool f_intra = (id0 != id3);
  const int hl = (idv[1] == id0) ? ((idv[2] == id0) ? ((idv[3] == id0) ? 4 : 3) : 2) : 1;
  const int tl = (idv[2] == id3) ? ((idv[1] == id3) ? ((idv[0] == id3) ? 4 : 3) : 2) : 1;
  float hx = 0.f, hy = 0.f, hz = 0.f, tx = 0.f, ty = 0.f, tz = 0.f;
  #pragma unroll
  for (int j = 0; j < 4; ++j) {
    if (j < hl)      { hx += px[j]; hy += py[j]; hz += pz[j]; }
    if (j >= 4 - tl) { tx += px[j]; ty += py[j]; tz += pz[j]; }
  }
  // interior complete runs (lane spans >=3 rays; rare) -> direct flush
  {
    int ilo = hl, ihi = 3 - tl;
    if (ilo <= ihi) {
      if (ilo == ihi) {
        atomicAdd(&out[3 * idv[ilo] + 0], px[ilo]);
        atomicAdd(&out[3 * idv[ilo] + 1], py[ilo]);
        atomicAdd(&out[3 * idv[ilo] + 2], pz[ilo]);
      } else if (idv[ilo] == idv[ihi]) {
        atomicAdd(&out[3 * idv[ilo] + 0], px[ilo] + px[ihi]);
        atomicAdd(&out[3 * idv[ilo] + 1], py[ilo] + py[ihi]);
        atomicAdd(&out[3 * idv[ilo] + 2], pz[ilo] + pz[ihi]);
      } else {
        atomicAdd(&out[3 * idv[ilo] + 0], px[ilo]);
        atomicAdd(&out[3 * idv[ilo] + 1], py[ilo]);
        atomicAdd(&out[3 * idv[ilo] + 2], pz[ilo]);
        atomicAdd(&out[3 * idv[ihi] + 0], px[ihi]);
        atomicAdd(&out[3 * idv[ihi] + 1], py[ihi]);
        atomicAdd(&out[3 * idv[ihi] + 2], pz[ihi]);
      }
    }
  }

  // ballot-based segmented inclusive scan over tail partials
  const int prev_tid = __shfl_up(id3, 1, 64);
  const int fl = (lane == 0 || f_intra || prev_tid != id0) ? 1 : 0;
  const unsigned long long heads = __ballot(fl);        // lane0 always set
  const unsigned long long below = heads & (~0ull >> (63 - lane));
  const int start = 63 - __clzll(below);                // this lane's run head
  float sx = tx, sy = ty, sz = tz;
  #pragma unroll
  for (int off = 1; off < 64; off <<= 1) {
    float ox = __shfl_up(sx, off, 64);
    float oy = __shfl_up(sy, off, 64);
    float oz = __shfl_up(sz, off, 64);
    if (lane - off >= start) { sx += ox; sy += oy; sz += oz; }
  }

  // head-run flush (run ending inside this lane's head prefix)
  const float pSx = __shfl_up(sx, 1, 64);
  const float pSy = __shfl_up(sy, 1, 64);
  const float pSz = __shfl_up(sz, 1, 64);
  if (f_intra) {
    const bool link = (lane > 0) && (prev_tid == id0);
    atomicAdd(&out[3 * id0 + 0], hx + (link ? pSx : 0.f));
    atomicAdd(&out[3 * id0 + 1], hy + (link ? pSy : 0.f));
    atomicAdd(&out[3 * id0 + 2], hz + (link ? pSz : 0.f));
  }

  // tail-run flush: last lane of each run within the wave
  const int next_hid = __shfl_down(id0, 1, 64);
  if (lane == 63 || next_hid != id3) {
    atomicAdd(&out[3 * id3 + 0], sx);
    atomicAdd(&out[3 * id3 + 1], sy);
    atomicAdd(&out[3 * id3 + 2], sz);
  }
}

__global__ __launch_bounds__(NTHREADS) void integrate_kernel(
    const int* __restrict__ ids, const float* __restrict__ rgb,
    const float* __restrict__ w, float* __restrict__ out, int n_samples) {
  const int lane = threadIdx.x & 63;
  const int wave = blockIdx.x * WPB + (threadIdx.x >> 6);
  const int W    = gridDim.x * WPB;
  const int nchunks = (n_samples + 255) >> 8;

  int c = wave;
  if (c >= nchunks) return;
  Chunk cur = load_chunk(ids, rgb, w, (long long)c * 256 + lane * 4, n_samples);
  for (;;) {
    const int cn = c + W;
    const bool has_next = (cn < nchunks);
    Chunk nxt;
    if (has_next)  // prefetch: issued before cur is consumed, stays in flight
      nxt = load_chunk(ids, rgb, w, (long long)cn * 256 + lane * 4, n_samples);
    process_chunk(cur, out, lane);
    if (!has_next) break;
    cur = nxt;
    c = cn;
  }
}

extern "C" void kernel_launch(void* const* d_in, const int* in_sizes, int n_in,
                              void* d_out, int out_size, void* d_ws, size_t ws_size,
                              hipStream_t stream) {
  const int*   segment_ids = (const int*)d_in[0];
  const float* rgb         = (const float*)d_in[1];
  const float* weights     = (const float*)d_in[2];
  float*       out         = (float*)d_out;

  const int n_samples = in_sizes[0];

  {  // zero output (all contributions arrive via atomics)
    int n4 = out_size / 4;  // out_size = n_rays*3 = 393216, divisible by 4
    int blocks = (n4 + NTHREADS - 1) / NTHREADS;
    zero_out_kernel<<<blocks, NTHREADS, 0, stream>>>((float4*)out, n4);
  }
  {
    int nchunks = (n_samples + 255) / 256;
    int blocks_needed = (nchunks + WPB - 1) / WPB;
    int blocks = blocks_needed < NBLOCKS ? blocks_needed : NBLOCKS;
    integrate_kernel<<<blocks, NTHREADS, 0, stream>>>(
        segment_ids, rgb, weights, out, n_samples);
  }
}

// Round 6
// 195.511 us; speedup vs baseline: 1.0265x; 1.0265x over previous
//
#include <hip/hip_runtime.h>

// out[r] = sum_{s in ray r} w[s] * rgb[s,:]  (segment_ids sorted, fp32)
// One-shot waves, barrier-free, LDS-free, DS-free (all cross-lane via DPP):
//   - each wave owns 256 contiguous samples (4/lane, aligned dwordx4 loads)
//   - per-lane run compression over its 4 sorted samples
//   - cross-lane merge via DPP segmented scan (row_shr 1/2/4/8 + row_bcast
//     15/31, predicated on ballot-derived run-head lane)
//   - one global atomicAdd triplet per run-end (out pre-zeroed)

#define NTHREADS 256

// DPP control encodings (gfx9/CDNA)
#define DPP_ROW_SHR(n)  (0x110 | (n))
#define DPP_ROW_BCAST15 0x142
#define DPP_ROW_BCAST31 0x143
#define DPP_WAVE_SHR1   0x138
#define DPP_WAVE_SHL1   0x130

template <int CTRL, int RM>
__device__ __forceinline__ float dpp_mov0_f(float v) {
  // masked-out rows / bound-invalid lanes produce 0
  return __int_as_float(
      __builtin_amdgcn_update_dpp(0, __float_as_int(v), CTRL, RM, 0xF, true));
}
template <int CTRL>
__device__ __forceinline__ int dpp_shift_i(int v, int old) {
  // bound_ctrl=false: lanes with no source keep `old` (sentinel)
  return __builtin_amdgcn_update_dpp(old, v, CTRL, 0xF, 0xF, false);
}
template <int CTRL>
__device__ __forceinline__ float dpp_shift_f(float v) {
  return __int_as_float(
      __builtin_amdgcn_update_dpp(0, __float_as_int(v), CTRL, 0xF, 0xF, false));
}

__global__ __launch_bounds__(NTHREADS) void zero_out_kernel(float4* __restrict__ out4,
                                                            int n4) {
  int i = blockIdx.x * blockDim.x + threadIdx.x;
  if (i < n4) out4[i] = make_float4(0.f, 0.f, 0.f, 0.f);
}

__global__ __launch_bounds__(NTHREADS) void integrate_kernel(
    const int* __restrict__ ids, const float* __restrict__ rgb,
    const float* __restrict__ w, float* __restrict__ out, int n_samples) {
  const int lane = threadIdx.x & 63;
  const long long t0 = (long long)(blockIdx.x * blockDim.x + threadIdx.x) * 4;

  int idv[4];
  float px[4], py[4], pz[4];
  if (t0 + 3 < n_samples) {  // aligned fast path (t0 % 4 == 0)
    const int4   id4 = *(const int4*)(ids + t0);
    const float4 w4  = *(const float4*)(w + t0);
    const float4 r0  = *(const float4*)(rgb + 3 * t0);
    const float4 r1  = *(const float4*)(rgb + 3 * t0 + 4);
    const float4 r2  = *(const float4*)(rgb + 3 * t0 + 8);
    idv[0] = id4.x; idv[1] = id4.y; idv[2] = id4.z; idv[3] = id4.w;
    px[0] = r0.x * w4.x; py[0] = r0.y * w4.x; pz[0] = r0.z * w4.x;
    px[1] = r0.w * w4.y; py[1] = r1.x * w4.y; pz[1] = r1.y * w4.y;
    px[2] = r1.z * w4.z; py[2] = r1.w * w4.z; pz[2] = r2.x * w4.z;
    px[3] = r2.y * w4.w; py[3] = r2.z * w4.w; pz[3] = r2.w * w4.w;
  } else {  // padded tail: pads merge into last run with zero contribution
    int last = ids[n_samples - 1];
    #pragma unroll
    for (int j = 0; j < 4; ++j) {
      long long s = t0 + j;
      if (s < n_samples) {
        idv[j] = ids[s];
        float ww = w[s];
        px[j] = rgb[3 * s + 0] * ww;
        py[j] = rgb[3 * s + 1] * ww;
        pz[j] = rgb[3 * s + 2] * ww;
      } else {
        idv[j] = (j == 0) ? last : idv[j - 1];
        px[j] = py[j] = pz[j] = 0.f;
      }
    }
  }

  // ---- per-lane run compression (sorted: id0==id3 => all four equal) -----
  const int id0 = idv[0], id3 = idv[3];
  const bool f_intra = (id0 != id3);
  const int hl = (idv[1] == id0) ? ((idv[2] == id0) ? ((idv[3] == id0) ? 4 : 3) : 2) : 1;
  const int tl = (idv[2] == id3) ? ((idv[1] == id3) ? ((idv[0] == id3) ? 4 : 3) : 2) : 1;
  float hx = 0.f, hy = 0.f, hz = 0.f, tx = 0.f, ty = 0.f, tz = 0.f;
  #pragma unroll
  for (int j = 0; j < 4; ++j) {
    if (j < hl)      { hx += px[j]; hy += py[j]; hz += pz[j]; }
    if (j >= 4 - tl) { tx += px[j]; ty += py[j]; tz += pz[j]; }
  }
  // interior complete runs (lane spans >=3 rays; rare) -> direct flush
  {
    int ilo = hl, ihi = 3 - tl;
    if (ilo <= ihi) {
      if (ilo == ihi) {
        atomicAdd(&out[3 * idv[ilo] + 0], px[ilo]);
        atomicAdd(&out[3 * idv[ilo] + 1], py[ilo]);
        atomicAdd(&out[3 * idv[ilo] + 2], pz[ilo]);
      } else if (idv[ilo] == idv[ihi]) {
        atomicAdd(&out[3 * idv[ilo] + 0], px[ilo] + px[ihi]);
        atomicAdd(&out[3 * idv[ilo] + 1], py[ilo] + py[ihi]);
        atomicAdd(&out[3 * idv[ilo] + 2], pz[ilo] + pz[ihi]);
      } else {
        atomicAdd(&out[3 * idv[ilo] + 0], px[ilo]);
        atomicAdd(&out[3 * idv[ilo] + 1], py[ilo]);
        atomicAdd(&out[3 * idv[ilo] + 2], pz[ilo]);
        atomicAdd(&out[3 * idv[ihi] + 0], px[ihi]);
        atomicAdd(&out[3 * idv[ihi] + 1], py[ihi]);
        atomicAdd(&out[3 * idv[ihi] + 2], pz[ihi]);
      }
    }
  }

  // ---- segmented inclusive scan over tail partials, pure DPP -------------
  const int prev_tid = dpp_shift_i<DPP_WAVE_SHR1>(id3, -1);  // lane0 -> -1
  const int fl = (f_intra || prev_tid != id0) ? 1 : 0;       // lane0: fl=1
  const unsigned long long heads = __ballot(fl);
  const unsigned long long below = heads & (~0ull >> (63 - lane));
  const int start = 63 - __clzll(below);  // this lane's run-head lane index

  float sx = tx, sy = ty, sz = tz;
  #pragma unroll
  for (int n = 1; n <= 8; n <<= 1) {  // intra-row (16-lane) segmented scan
    const bool c = (lane - n) >= start;
    float ox, oy, oz;
    switch (n) {  // CTRL must be a compile-time constant
      case 1: ox = dpp_mov0_f<DPP_ROW_SHR(1), 0xF>(sx);
              oy = dpp_mov0_f<DPP_ROW_SHR(1), 0xF>(sy);
              oz = dpp_mov0_f<DPP_ROW_SHR(1), 0xF>(sz); break;
      case 2: ox = dpp_mov0_f<DPP_ROW_SHR(2), 0xF>(sx);
              oy = dpp_mov0_f<DPP_ROW_SHR(2), 0xF>(sy);
              oz = dpp_mov0_f<DPP_ROW_SHR(2), 0xF>(sz); break;
      case 4: ox = dpp_mov0_f<DPP_ROW_SHR(4), 0xF>(sx);
              oy = dpp_mov0_f<DPP_ROW_SHR(4), 0xF>(sy);
              oz = dpp_mov0_f<DPP_ROW_SHR(4), 0xF>(sz); break;
      default: ox = dpp_mov0_f<DPP_ROW_SHR(8), 0xF>(sx);
               oy = dpp_mov0_f<DPP_ROW_SHR(8), 0xF>(sy);
               oz = dpp_mov0_f<DPP_ROW_SHR(8), 0xF>(sz); break;
    }
    if (c) { sx += ox; sy += oy; sz += oz; }
  }
  {  // row-crossing step 1: lane15 -> row1, lane47 -> row3 (rows 1,3 only)
    const bool c = start < (lane & ~15);  // src lane = (lane&~15)-1 = 15 or 47
    float ox = dpp_mov0_f<DPP_ROW_BCAST15, 0xA>(sx);
    float oy = dpp_mov0_f<DPP_ROW_BCAST15, 0xA>(sy);
    float oz = dpp_mov0_f<DPP_ROW_BCAST15, 0xA>(sz);
    if (c) { sx += ox; sy += oy; sz += oz; }
  }
  {  // row-crossing step 2: lane31 -> rows 2,3
    const bool c = start <= 31 && lane >= 32;
    float ox = dpp_mov0_f<DPP_ROW_BCAST31, 0xC>(sx);
    float oy = dpp_mov0_f<DPP_ROW_BCAST31, 0xC>(sy);
    float oz = dpp_mov0_f<DPP_ROW_BCAST31, 0xC>(sz);
    if (c) { sx += ox; sy += oy; sz += oz; }
  }

  // head-run flush (run ending inside this lane's head prefix)
  const float pSx = dpp_shift_f<DPP_WAVE_SHR1>(sx);  // lane0 -> 0
  const float pSy = dpp_shift_f<DPP_WAVE_SHR1>(sy);
  const float pSz = dpp_shift_f<DPP_WAVE_SHR1>(sz);
  if (f_intra) {
    const bool link = (lane > 0) && (prev_tid == id0);
    atomicAdd(&out[3 * id0 + 0], hx + (link ? pSx : 0.f));
    atomicAdd(&out[3 * id0 + 1], hy + (link ? pSy : 0.f));
    atomicAdd(&out[3 * id0 + 2], hz + (link ? pSz : 0.f));
  }

  // tail-run flush: last lane of each run within the wave
  const int next_hid = dpp_shift_i<DPP_WAVE_SHL1>(id0, -1);  // lane63 -> -1
  if (next_hid != id3) {  // lane63 sentinel forces flush
    atomicAdd(&out[3 * id3 + 0], sx);
    atomicAdd(&out[3 * id3 + 1], sy);
    atomicAdd(&out[3 * id3 + 2], sz);
  }
}

extern "C" void kernel_launch(void* const* d_in, const int* in_sizes, int n_in,
                              void* d_out, int out_size, void* d_ws, size_t ws_size,
                              hipStream_t stream) {
  const int*   segment_ids = (const int*)d_in[0];
  const float* rgb         = (const float*)d_in[1];
  const float* weights     = (const float*)d_in[2];
  float*       out         = (float*)d_out;

  const int n_samples = in_sizes[0];

  {  // zero output (all contributions arrive via atomics)
    int n4 = out_size / 4;  // out_size = n_rays*3 = 393216, divisible by 4
    int blocks = (n4 + NTHREADS - 1) / NTHREADS;
    zero_out_kernel<<<blocks, NTHREADS, 0, stream>>>((float4*)out, n4);
  }
  {
    int spb = NTHREADS * 4;  // samples per block
    int blocks = (n_samples + spb - 1) / spb;
    integrate_kernel<<<blocks, NTHREADS, 0, stream>>>(
        segment_ids, rgb, weights, out, n_samples);
  }
}